// Round 2
// baseline (2213.538 us; speedup 1.0000x reference)
//
#include <hip/hip_runtime.h>
#include <stdint.h>

#define GAS __attribute__((address_space(1)))
#define LAS __attribute__((address_space(3)))

typedef __bf16 bf16x8 __attribute__((ext_vector_type(8)));
typedef _Float16 f16x8 __attribute__((ext_vector_type(8)));
typedef float f32x4 __attribute__((ext_vector_type(4)));

__device__ __forceinline__ unsigned short f2bf(float f) {
  unsigned u = __float_as_uint(f);
  unsigned r = (u + 0x7FFFu + ((u >> 16) & 1u)) >> 16;
  return (unsigned short)r;
}

__device__ __forceinline__ float sigmoidf(float x) {
  return 1.f / (1.f + expf(-x));
}

// ---------------- gather: x_bf16 [4096,512] from seq; word_emb f32 [64,512] ----
__global__ __launch_bounds__(128) void k_gather(
    const float* __restrict__ emb, const int* __restrict__ seq,
    const int* __restrict__ word, unsigned short* __restrict__ xbf,
    float* __restrict__ wemb) {
  int row = blockIdx.x;
  int tid = threadIdx.x;
  if (row < 4096) {
    const float* src = emb + (size_t)seq[row] * 512;
    unsigned short* dst = xbf + (size_t)row * 512;
    for (int e = tid; e < 512; e += 128) dst[e] = f2bf(src[e]);
  } else {
    int b = row - 4096;
    const float* src = emb + (size_t)word[b] * 512;
    float* dst = wemb + (size_t)b * 512;
    for (int e = tid; e < 512; e += 128) dst[e] = src[e];
  }
}

// ---------------- weight conversion: wih_bf [1536,512], dec_bf [32000,512] ----
__global__ __launch_bounds__(128) void k_conv(
    const float* __restrict__ Wih, const float* __restrict__ decW,
    unsigned short* __restrict__ wih_bf, unsigned short* __restrict__ dec_bf) {
  int row = blockIdx.x;
  int tid = threadIdx.x;
  if (row < 1536) {
    const float* s = Wih + (size_t)row * 512;
    unsigned short* d = wih_bf + (size_t)row * 512;
    for (int e = tid; e < 512; e += 128) d[e] = f2bf(s[e]);
  } else {
    int o = row - 1536;
    const float* s = decW + (size_t)o * 512;
    unsigned short* d = dec_bf + (size_t)o * 512;
    for (int e = tid; e < 512; e += 128) d[e] = f2bf(s[e]);
  }
}

// ---------------- step-invariant gate preactivations from word_emb ------------
__global__ __launch_bounds__(256) void k_pre(
    const float* __restrict__ ztW, const float* __restrict__ ztb,
    const float* __restrict__ rtW, const float* __restrict__ rtb,
    const float* __restrict__ wemb, float* __restrict__ ztp,
    float* __restrict__ rtp) {
  int idx = blockIdx.x * 256 + threadIdx.x;
  int b = idx >> 10, o = idx & 1023;
  const float4* we = (const float4*)(wemb + (size_t)b * 512);
  const float4* wr;
  float acc;
  if (o < 512) { wr = (const float4*)(ztW + (size_t)o * 1024); acc = ztb[o]; }
  else { wr = (const float4*)(rtW + (size_t)(o - 512) * 1024); acc = rtb[o - 512]; }
  for (int c = 0; c < 128; ++c) {
    float4 w = wr[c], e = we[c];
    acc += w.x * e.x + w.y * e.y + w.z * e.z + w.w * e.w;
  }
  if (o < 512) ztp[(size_t)b * 512 + o] = acc;
  else rtp[(size_t)b * 512 + (o - 512)] = acc;
}

// ---------------- bf16 GEMM, C[m,n] = sum_k A[m,k]*B[n,k] + bias[n] ----------
__global__ __launch_bounds__(256) void k_gemm_bt(
    const unsigned short* __restrict__ A, const unsigned short* __restrict__ B,
    float* __restrict__ C, const float* __restrict__ bias,
    int M, int N, int K) {
  __shared__ __align__(16) unsigned short As[128 * 32];
  __shared__ __align__(16) unsigned short Bs[128 * 32];
  int nt = N >> 7;
  int nwg = gridDim.x;
  int bid = blockIdx.x;
  int swz = (bid & 7) * (nwg >> 3) + (bid >> 3);  // XCD swizzle (nwg % 8 == 0)
  int m0 = (swz / nt) << 7, n0 = (swz % nt) << 7;
  int tid = threadIdx.x;
  int l = tid & 63, w = tid >> 6;
  int wr = w >> 1, wc = w & 1;
  int lr = l & 15, lk = l >> 4;
  f32x4 acc[4][4] = {};
  for (int k0 = 0; k0 < K; k0 += 32) {
#pragma unroll
    for (int i = 0; i < 2; ++i) {
      int c = w * 2 + i;
      int off = c * 1024 + l * 16;
      int row = off >> 6, kb = off & 63;
      const char* ga = (const char*)A + ((size_t)(m0 + row) * K + k0) * 2 + kb;
      const char* gb = (const char*)B + ((size_t)(n0 + row) * K + k0) * 2 + kb;
      __builtin_amdgcn_global_load_lds((const GAS void*)ga,
                                       (LAS void*)((char*)As + c * 1024), 16, 0, 0);
      __builtin_amdgcn_global_load_lds((const GAS void*)gb,
                                       (LAS void*)((char*)Bs + c * 1024), 16, 0, 0);
    }
    asm volatile("s_waitcnt vmcnt(0)" ::: "memory");
    __syncthreads();
    bf16x8 af[4], bfr[4];
#pragma unroll
    for (int i = 0; i < 4; ++i)
      af[i] = *(const bf16x8*)&As[(wr * 64 + i * 16 + lr) * 32 + lk * 8];
#pragma unroll
    for (int i = 0; i < 4; ++i)
      bfr[i] = *(const bf16x8*)&Bs[(wc * 64 + i * 16 + lr) * 32 + lk * 8];
#pragma unroll
    for (int i = 0; i < 4; ++i)
#pragma unroll
      for (int jj = 0; jj < 4; ++jj)
        acc[i][jj] = __builtin_amdgcn_mfma_f32_16x16x32_bf16(af[i], bfr[jj], acc[i][jj], 0, 0, 0);
    __syncthreads();
  }
#pragma unroll
  for (int jj = 0; jj < 4; ++jj) {
    int col = n0 + wc * 64 + jj * 16 + lr;
    float bv = bias ? bias[col] : 0.f;
#pragma unroll
    for (int i = 0; i < 4; ++i) {
      int rb = m0 + wr * 64 + i * 16 + lk * 4;
#pragma unroll
      for (int q = 0; q < 4; ++q)
        C[(size_t)(rb + q) * N + col] = acc[i][jj][q] + bv;
    }
  }
}

// ---------------- recurrence: 32 wgs, output-column ownership, LDS weights ----
// wg g owns state cols [16g, 16g+16). Weights (f16) live in LDS for all 64 steps.
// 3 lightweight grid barriers per step (all 32 wgs co-resident: 116KB LDS -> 1 wg/CU).
struct RnnP {
  const float *Whh, *ztW, *rtW, *htW;
  const float *gi, *ztp, *rtp, *wemb, *inith, *bhh, *htb;
  _Float16 *hcur, *hgru, *rw;
  unsigned short *outsb;
  float *hfin;
  unsigned *bar;
};

__device__ __forceinline__ void gbar(unsigned* ctr, unsigned target) {
  __threadfence();
  __syncthreads();
  if (threadIdx.x == 0) {
    __hip_atomic_fetch_add(ctr, 1u, __ATOMIC_RELEASE, __HIP_MEMORY_SCOPE_AGENT);
    while (__hip_atomic_load(ctr, __ATOMIC_ACQUIRE, __HIP_MEMORY_SCOPE_AGENT) < target)
      __builtin_amdgcn_s_sleep(1);
  }
  __syncthreads();
}

// MFMA phase: acc[n] += A[64,512] (rows 16w..16w+16) x WL-slice (nt n-tiles of 16 cols)
template <int NT>
__device__ __forceinline__ void mm_phase(f32x4* acc, const _Float16* __restrict__ A,
                                         const _Float16* WLrow, int w, int lr, int lk) {
  const _Float16* arow = A + ((size_t)(16 * w + lr)) * 512 + lk * 8;
#pragma unroll 4
  for (int k0 = 0; k0 < 512; k0 += 32) {
    f16x8 a = *(const f16x8*)(arow + k0);
#pragma unroll
    for (int n = 0; n < NT; ++n) {
      f16x8 bb = *(const f16x8*)(WLrow + (n * 16 + lr) * 520 + k0 + lk * 8);
      acc[n] = __builtin_amdgcn_mfma_f32_16x16x32_f16(a, bb, acc[n], 0, 0, 0);
    }
  }
}

__global__ __launch_bounds__(256) void k_rnn2(RnnP p) {
  const int g = blockIdx.x, tid = threadIdx.x;
  const int w = tid >> 6, l = tid & 63;
  const int lr = l & 15, lk = l >> 4;
  // 112 rows x 520 halfs (512 + 8 pad -> row stride 1040B, 16B aligned, ~2-way banks)
  __shared__ _Float16 WL[112 * 520];
  // ---- one-time: weights f32 -> f16 into LDS ----
  for (int idx = tid; idx < 112 * 512; idx += 256) {
    int rr = idx >> 9, e = idx & 511;
    const float* src;
    if (rr < 48) {
      int gate = rr >> 4, i = rr & 15;
      src = p.Whh + ((size_t)(gate * 512 + g * 16 + i)) * 512 + e;
    } else if (rr < 96) {
      int r2 = rr - 48, gate = r2 >> 4, i = r2 & 15;
      const float* base = gate == 0 ? p.ztW : (gate == 1 ? p.rtW : p.htW);
      src = base + ((size_t)(g * 16 + i)) * 1024 + 512 + e;
    } else {
      int i = rr - 96;
      src = p.htW + ((size_t)(g * 16 + i)) * 1024 + e;
    }
    WL[rr * 520 + e] = (_Float16)(*src);
  }
  // ---- per-lane owned coordinates: col j, batch rows brow..brow+3 ----
  const int j = g * 16 + lr;
  const int brow = 16 * w + lk * 4;
  f32x4 hprev, zp, rp, wev;
#pragma unroll
  for (int q = 0; q < 4; ++q) {
    int b = brow + q;
    hprev[q] = p.inith[(size_t)b * 512 + j];
    zp[q] = p.ztp[(size_t)b * 512 + j];
    rp[q] = p.rtp[(size_t)b * 512 + j];
    wev[q] = p.wemb[(size_t)b * 512 + j];
    p.hcur[(size_t)b * 512 + j] = (_Float16)hprev[q];
  }
  const float br = p.bhh[j], bz = p.bhh[512 + j], bn = p.bhh[1024 + j];
  const float bht = p.htb[j];
  unsigned ord = 1;
  gbar(p.bar, 32 * ord); ord++;
  for (int t = 0; t < 64; ++t) {
    // ---- phase 1: gates r,z,n ; h_gru ----
    f32x4 acc1[3] = {};
    mm_phase<3>(acc1, p.hcur, &WL[0], w, lr, lk);
    const float* git = p.gi + (size_t)t * 64 * 1536;
    f32x4 hg;
#pragma unroll
    for (int q = 0; q < 4; ++q) {
      int b = brow + q;
      float ir = git[(size_t)b * 1536 + j];
      float iz = git[(size_t)b * 1536 + 512 + j];
      float inn = git[(size_t)b * 1536 + 1024 + j];
      float r = sigmoidf(ir + br + acc1[0][q]);
      float z = sigmoidf(iz + bz + acc1[1][q]);
      float n = tanhf(inn + r * (acc1[2][q] + bn));
      float hgq = (1.f - z) * n + z * hprev[q];
      hg[q] = hgq;
      p.hgru[(size_t)b * 512 + j] = (_Float16)hgq;
      p.outsb[((size_t)t * 64 + b) * 512 + j] = f2bf(hgq);
    }
    gbar(p.bar, 32 * ord); ord++;
    // ---- phase 2: zt, rt, htB ----
    f32x4 acc2[3] = {};
    mm_phase<3>(acc2, p.hgru, &WL[48 * 520], w, lr, lk);
    f32x4 zt, htB;
#pragma unroll
    for (int q = 0; q < 4; ++q) {
      int b = brow + q;
      float ztq = sigmoidf(zp[q] + acc2[0][q]);
      float rtq = sigmoidf(rp[q] + acc2[1][q]);
      zt[q] = ztq;
      htB[q] = acc2[2][q];
      p.rw[(size_t)b * 512 + j] = (_Float16)(rtq * wev[q]);
    }
    gbar(p.bar, 32 * ord); ord++;
    // ---- phase 3: htA ; h_new ----
    f32x4 acc3[1] = {};
    mm_phase<1>(acc3, p.rw, &WL[96 * 520], w, lr, lk);
#pragma unroll
    for (int q = 0; q < 4; ++q) {
      int b = brow + q;
      float htl = tanhf(acc3[0][q] + htB[q] + bht);
      float hn2 = (1.f - zt[q]) * hg[q] + zt[q] * htl;
      hprev[q] = hn2;
      p.hcur[(size_t)b * 512 + j] = (_Float16)hn2;
      if (t == 63) p.hfin[(size_t)b * 512 + j] = hn2;
    }
    gbar(p.bar, 32 * ord); ord++;
  }
}

extern "C" void kernel_launch(void* const* d_in, const int* in_sizes, int n_in,
                              void* d_out, int out_size, void* d_ws, size_t ws_size,
                              hipStream_t stream) {
  const float* emb   = (const float*)d_in[0];
  const float* Wih   = (const float*)d_in[1];
  const float* Whh   = (const float*)d_in[2];
  const float* bih   = (const float*)d_in[3];
  const float* bhh   = (const float*)d_in[4];
  const float* ztW   = (const float*)d_in[5];
  const float* ztb   = (const float*)d_in[6];
  const float* rtW   = (const float*)d_in[7];
  const float* rtb   = (const float*)d_in[8];
  const float* htW   = (const float*)d_in[9];
  const float* htb   = (const float*)d_in[10];
  const float* decW  = (const float*)d_in[11];
  const float* decb  = (const float*)d_in[12];
  const float* inith = (const float*)d_in[13];
  const int* word    = (const int*)d_in[14];
  const int* seq     = (const int*)d_in[15];
  float* out = (float*)d_out;

  char* ws = (char*)d_ws;
  size_t off = 0;
  auto alloc = [&](size_t bytes) {
    size_t o = off;
    off += (bytes + 255) & ~(size_t)255;
    return o;
  };
  unsigned short* xbf   = (unsigned short*)(ws + alloc(4096ull * 512 * 2));
  unsigned short* wihbf = (unsigned short*)(ws + alloc(1536ull * 512 * 2));
  unsigned short* decbf = (unsigned short*)(ws + alloc(32000ull * 512 * 2));
  float* wemb           = (float*)(ws + alloc(64ull * 512 * 4));
  float* ztp            = (float*)(ws + alloc(64ull * 512 * 4));
  float* rtp            = (float*)(ws + alloc(64ull * 512 * 4));
  float* gi             = (float*)(ws + alloc(4096ull * 1536 * 4));
  unsigned short* outsb = (unsigned short*)(ws + alloc(4096ull * 512 * 2));
  _Float16* hcur        = (_Float16*)(ws + alloc(64ull * 512 * 2));
  _Float16* hgru        = (_Float16*)(ws + alloc(64ull * 512 * 2));
  _Float16* rw          = (_Float16*)(ws + alloc(64ull * 512 * 2));
  unsigned* bar         = (unsigned*)(ws + alloc(256));

  hipLaunchKernelGGL(k_gather, dim3(4160), dim3(128), 0, stream,
                     emb, seq, word, xbf, wemb);
  hipLaunchKernelGGL(k_conv, dim3(33536), dim3(128), 0, stream,
                     Wih, decW, wihbf, decbf);
  hipLaunchKernelGGL(k_pre, dim3(256), dim3(256), 0, stream,
                     ztW, ztb, rtW, rtb, wemb, ztp, rtp);
  hipLaunchKernelGGL(k_gemm_bt, dim3(384), dim3(256), 0, stream,
                     xbf, wihbf, gi, bih, 4096, 1536, 512);
  hipMemsetAsync(bar, 0, 256, stream);
  RnnP p{Whh, ztW, rtW, htW, gi, ztp, rtp, wemb, inith, bhh, htb,
         hcur, hgru, rw, outsb, out + 4096ull * 32000, bar};
  hipLaunchKernelGGL(k_rnn2, dim3(32), dim3(256), 0, stream, p);
  hipLaunchKernelGGL(k_gemm_bt, dim3(8000), dim3(256), 0, stream,
                     outsb, decbf, out, decb, 4096, 32000, 512);
}

// Round 3
// 1515.751 us; speedup vs baseline: 1.4604x; 1.4604x over previous
//
#include <hip/hip_runtime.h>
#include <stdint.h>

#define GAS __attribute__((address_space(1)))
#define LAS __attribute__((address_space(3)))

typedef __bf16 bf16x8 __attribute__((ext_vector_type(8)));
typedef _Float16 f16x8 __attribute__((ext_vector_type(8)));
typedef float f32x4 __attribute__((ext_vector_type(4)));

__device__ __forceinline__ unsigned short f2bf(float f) {
  unsigned u = __float_as_uint(f);
  unsigned r = (u + 0x7FFFu + ((u >> 16) & 1u)) >> 16;
  return (unsigned short)r;
}

__device__ __forceinline__ float sigmoidf(float x) {
  return 1.f / (1.f + expf(-x));
}

// ---- device-coherent (L2-bypassing) exchange primitives: no fences needed ----
__device__ __forceinline__ void st2c(_Float16* p, _Float16 v) {
  unsigned short u = __builtin_bit_cast(unsigned short, v);
  __hip_atomic_store((unsigned short*)p, u, __ATOMIC_RELAXED, __HIP_MEMORY_SCOPE_AGENT);
}

__device__ __forceinline__ f16x8 ld8c(const _Float16* p) {
  unsigned long long a =
      __hip_atomic_load((const unsigned long long*)p, __ATOMIC_RELAXED, __HIP_MEMORY_SCOPE_AGENT);
  unsigned long long b =
      __hip_atomic_load((const unsigned long long*)(p + 4), __ATOMIC_RELAXED, __HIP_MEMORY_SCOPE_AGENT);
  union { unsigned long long u[2]; f16x8 v; } c;
  c.u[0] = a; c.u[1] = b;
  return c.v;
}

// ---------------- gather: x_bf16 [4096,512] from seq; word_emb f32 [64,512] ----
__global__ __launch_bounds__(128) void k_gather(
    const float* __restrict__ emb, const int* __restrict__ seq,
    const int* __restrict__ word, unsigned short* __restrict__ xbf,
    float* __restrict__ wemb) {
  int row = blockIdx.x;
  int tid = threadIdx.x;
  if (row < 4096) {
    const float* src = emb + (size_t)seq[row] * 512;
    unsigned short* dst = xbf + (size_t)row * 512;
    for (int e = tid; e < 512; e += 128) dst[e] = f2bf(src[e]);
  } else {
    int b = row - 4096;
    const float* src = emb + (size_t)word[b] * 512;
    float* dst = wemb + (size_t)b * 512;
    for (int e = tid; e < 512; e += 128) dst[e] = src[e];
  }
}

// ---------------- weight conversion: wih_bf [1536,512], dec_bf [32000,512] ----
__global__ __launch_bounds__(128) void k_conv(
    const float* __restrict__ Wih, const float* __restrict__ decW,
    unsigned short* __restrict__ wih_bf, unsigned short* __restrict__ dec_bf) {
  int row = blockIdx.x;
  int tid = threadIdx.x;
  if (row < 1536) {
    const float* s = Wih + (size_t)row * 512;
    unsigned short* d = wih_bf + (size_t)row * 512;
    for (int e = tid; e < 512; e += 128) d[e] = f2bf(s[e]);
  } else {
    int o = row - 1536;
    const float* s = decW + (size_t)o * 512;
    unsigned short* d = dec_bf + (size_t)o * 512;
    for (int e = tid; e < 512; e += 128) d[e] = f2bf(s[e]);
  }
}

// ---------------- step-invariant gate preactivations from word_emb ------------
__global__ __launch_bounds__(256) void k_pre(
    const float* __restrict__ ztW, const float* __restrict__ ztb,
    const float* __restrict__ rtW, const float* __restrict__ rtb,
    const float* __restrict__ wemb, float* __restrict__ ztp,
    float* __restrict__ rtp) {
  int idx = blockIdx.x * 256 + threadIdx.x;
  int b = idx >> 10, o = idx & 1023;
  const float4* we = (const float4*)(wemb + (size_t)b * 512);
  const float4* wr;
  float acc;
  if (o < 512) { wr = (const float4*)(ztW + (size_t)o * 1024); acc = ztb[o]; }
  else { wr = (const float4*)(rtW + (size_t)(o - 512) * 1024); acc = rtb[o - 512]; }
  for (int c = 0; c < 128; ++c) {
    float4 w = wr[c], e = we[c];
    acc += w.x * e.x + w.y * e.y + w.z * e.z + w.w * e.w;
  }
  if (o < 512) ztp[(size_t)b * 512 + o] = acc;
  else rtp[(size_t)b * 512 + (o - 512)] = acc;
}

// ---------------- bf16 GEMM, C[m,n] = sum_k A[m,k]*B[n,k] + bias[n] ----------
__global__ __launch_bounds__(256) void k_gemm_bt(
    const unsigned short* __restrict__ A, const unsigned short* __restrict__ B,
    float* __restrict__ C, const float* __restrict__ bias,
    int M, int N, int K) {
  __shared__ __align__(16) unsigned short As[128 * 32];
  __shared__ __align__(16) unsigned short Bs[128 * 32];
  int nt = N >> 7;
  int nwg = gridDim.x;
  int bid = blockIdx.x;
  int swz = (bid & 7) * (nwg >> 3) + (bid >> 3);  // XCD swizzle (nwg % 8 == 0)
  int m0 = (swz / nt) << 7, n0 = (swz % nt) << 7;
  int tid = threadIdx.x;
  int l = tid & 63, w = tid >> 6;
  int wr = w >> 1, wc = w & 1;
  int lr = l & 15, lk = l >> 4;
  f32x4 acc[4][4] = {};
  for (int k0 = 0; k0 < K; k0 += 32) {
#pragma unroll
    for (int i = 0; i < 2; ++i) {
      int c = w * 2 + i;
      int off = c * 1024 + l * 16;
      int row = off >> 6, kb = off & 63;
      const char* ga = (const char*)A + ((size_t)(m0 + row) * K + k0) * 2 + kb;
      const char* gb = (const char*)B + ((size_t)(n0 + row) * K + k0) * 2 + kb;
      __builtin_amdgcn_global_load_lds((const GAS void*)ga,
                                       (LAS void*)((char*)As + c * 1024), 16, 0, 0);
      __builtin_amdgcn_global_load_lds((const GAS void*)gb,
                                       (LAS void*)((char*)Bs + c * 1024), 16, 0, 0);
    }
    asm volatile("s_waitcnt vmcnt(0)" ::: "memory");
    __syncthreads();
    bf16x8 af[4], bfr[4];
#pragma unroll
    for (int i = 0; i < 4; ++i)
      af[i] = *(const bf16x8*)&As[(wr * 64 + i * 16 + lr) * 32 + lk * 8];
#pragma unroll
    for (int i = 0; i < 4; ++i)
      bfr[i] = *(const bf16x8*)&Bs[(wc * 64 + i * 16 + lr) * 32 + lk * 8];
#pragma unroll
    for (int i = 0; i < 4; ++i)
#pragma unroll
      for (int jj = 0; jj < 4; ++jj)
        acc[i][jj] = __builtin_amdgcn_mfma_f32_16x16x32_bf16(af[i], bfr[jj], acc[i][jj], 0, 0, 0);
    __syncthreads();
  }
#pragma unroll
  for (int jj = 0; jj < 4; ++jj) {
    int col = n0 + wc * 64 + jj * 16 + lr;
    float bv = bias ? bias[col] : 0.f;
#pragma unroll
    for (int i = 0; i < 4; ++i) {
      int rb = m0 + wr * 64 + i * 16 + lk * 4;
#pragma unroll
      for (int q = 0; q < 4; ++q)
        C[(size_t)(rb + q) * N + col] = acc[i][jj][q] + bv;
    }
  }
}

// ---------------- recurrence: 32 wgs, output-column ownership, LDS weights ----
// wg g owns state cols [16g, 16g+16). Weights (f16) live in LDS for all 64 steps.
// Exchange via relaxed agent-scope (L2-bypassing) atomics; barrier is
// waitcnt + relaxed fetch_add + relaxed poll — NO cache maintenance ops.
struct RnnP {
  const float *Whh, *ztW, *rtW, *htW;
  const float *gi, *ztp, *rtp, *wemb, *inith, *bhh, *htb;
  _Float16 *hcur, *hgru, *rw;
  unsigned short *outsb;
  float *hfin;
  unsigned *bar;
};

__device__ __forceinline__ void gbar(unsigned* ctr, unsigned target) {
  asm volatile("s_waitcnt vmcnt(0)" ::: "memory");  // my sc1 stores are visible
  __syncthreads();                                   // whole wg drained & arrived
  if (threadIdx.x == 0) {
    __hip_atomic_fetch_add(ctr, 1u, __ATOMIC_RELAXED, __HIP_MEMORY_SCOPE_AGENT);
    while (__hip_atomic_load(ctr, __ATOMIC_RELAXED, __HIP_MEMORY_SCOPE_AGENT) < target)
      __builtin_amdgcn_s_sleep(4);
  }
  __syncthreads();
}

// acc[n] += A[64,512] (rows 16w..16w+16) x WL-slice; A read via coherent loads,
// all 16 fragments issued upfront for MLP.
template <int NT>
__device__ __forceinline__ void mm_phase(f32x4* acc, const _Float16* A,
                                         const _Float16* WLrow, int w, int lr, int lk) {
  f16x8 af[16];
  const _Float16* arow = A + ((size_t)(16 * w + lr)) * 512 + lk * 8;
#pragma unroll
  for (int c = 0; c < 16; ++c) af[c] = ld8c(arow + c * 32);
#pragma unroll
  for (int c = 0; c < 16; ++c) {
#pragma unroll
    for (int n = 0; n < NT; ++n) {
      f16x8 bb = *(const f16x8*)(WLrow + (n * 16 + lr) * 520 + c * 32 + lk * 8);
      acc[n] = __builtin_amdgcn_mfma_f32_16x16x32_f16(af[c], bb, acc[n], 0, 0, 0);
    }
  }
}

__global__ __launch_bounds__(256) void k_rnn2(RnnP p) {
  const int g = blockIdx.x, tid = threadIdx.x;
  const int w = tid >> 6, l = tid & 63;
  const int lr = l & 15, lk = l >> 4;
  // 112 rows x 520 halfs (512 + 8 pad -> row stride 1040B, ~2-way banks = free)
  __shared__ _Float16 WL[112 * 520];
  // ---- one-time: weights f32 -> f16 into LDS ----
  for (int idx = tid; idx < 112 * 512; idx += 256) {
    int rr = idx >> 9, e = idx & 511;
    const float* src;
    if (rr < 48) {
      int gate = rr >> 4, i = rr & 15;
      src = p.Whh + ((size_t)(gate * 512 + g * 16 + i)) * 512 + e;
    } else if (rr < 96) {
      int r2 = rr - 48, gate = r2 >> 4, i = r2 & 15;
      const float* base = gate == 0 ? p.ztW : (gate == 1 ? p.rtW : p.htW);
      src = base + ((size_t)(g * 16 + i)) * 1024 + 512 + e;
    } else {
      int i = rr - 96;
      src = p.htW + ((size_t)(g * 16 + i)) * 1024 + e;
    }
    WL[rr * 520 + e] = (_Float16)(*src);
  }
  // ---- per-lane owned coordinates: col j, batch rows brow..brow+3 ----
  const int j = g * 16 + lr;
  const int brow = 16 * w + lk * 4;
  f32x4 hprev, zp, rp, wev;
#pragma unroll
  for (int q = 0; q < 4; ++q) {
    int b = brow + q;
    hprev[q] = p.inith[(size_t)b * 512 + j];
    zp[q] = p.ztp[(size_t)b * 512 + j];
    rp[q] = p.rtp[(size_t)b * 512 + j];
    wev[q] = p.wemb[(size_t)b * 512 + j];
    st2c(&p.hcur[(size_t)b * 512 + j], (_Float16)hprev[q]);
  }
  const float br = p.bhh[j], bz = p.bhh[512 + j], bn = p.bhh[1024 + j];
  const float bht = p.htb[j];
  // gi prefetch registers (plain cached loads; gi is immutable input)
  float gir[12];
#pragma unroll
  for (int q = 0; q < 4; ++q) {
    const float* git = p.gi + (size_t)(brow + q) * 1536;
    gir[q * 3 + 0] = git[j];
    gir[q * 3 + 1] = git[512 + j];
    gir[q * 3 + 2] = git[1024 + j];
  }
  unsigned ord = 1;
  gbar(p.bar, 32 * ord); ord++;
  for (int t = 0; t < 64; ++t) {
    // ---- phase 1: gates r,z,n ; h_gru ----
    f32x4 acc1[3] = {};
    mm_phase<3>(acc1, p.hcur, &WL[0], w, lr, lk);
    f32x4 hg;
#pragma unroll
    for (int q = 0; q < 4; ++q) {
      int b = brow + q;
      float r = sigmoidf(gir[q * 3 + 0] + br + acc1[0][q]);
      float z = sigmoidf(gir[q * 3 + 1] + bz + acc1[1][q]);
      float n = tanhf(gir[q * 3 + 2] + r * (acc1[2][q] + bn));
      float hgq = (1.f - z) * n + z * hprev[q];
      hg[q] = hgq;
      st2c(&p.hgru[(size_t)b * 512 + j], (_Float16)hgq);
      p.outsb[((size_t)t * 64 + b) * 512 + j] = f2bf(hgq);
    }
    gbar(p.bar, 32 * ord); ord++;
    // ---- phase 2: zt, rt, htB ----
    f32x4 acc2[3] = {};
    mm_phase<3>(acc2, p.hgru, &WL[48 * 520], w, lr, lk);
    f32x4 zt, htB;
#pragma unroll
    for (int q = 0; q < 4; ++q) {
      int b = brow + q;
      float ztq = sigmoidf(zp[q] + acc2[0][q]);
      float rtq = sigmoidf(rp[q] + acc2[1][q]);
      zt[q] = ztq;
      htB[q] = acc2[2][q];
      st2c(&p.rw[(size_t)b * 512 + j], (_Float16)(rtq * wev[q]));
    }
    gbar(p.bar, 32 * ord); ord++;
    // ---- phase 3: htA ; h_new (prefetch next step's gi first, hides latency) ----
    if (t < 63) {
      const float* git = p.gi + (size_t)(t + 1) * 64 * 1536;
#pragma unroll
      for (int q = 0; q < 4; ++q) {
        const float* gb = git + (size_t)(brow + q) * 1536;
        gir[q * 3 + 0] = gb[j];
        gir[q * 3 + 1] = gb[512 + j];
        gir[q * 3 + 2] = gb[1024 + j];
      }
    }
    f32x4 acc3[1] = {};
    mm_phase<1>(acc3, p.rw, &WL[96 * 520], w, lr, lk);
#pragma unroll
    for (int q = 0; q < 4; ++q) {
      int b = brow + q;
      float htl = tanhf(acc3[0][q] + htB[q] + bht);
      float hn2 = (1.f - zt[q]) * hg[q] + zt[q] * htl;
      hprev[q] = hn2;
      if (t < 63) st2c(&p.hcur[(size_t)b * 512 + j], (_Float16)hn2);
      else p.hfin[(size_t)b * 512 + j] = hn2;
    }
    if (t < 63) { gbar(p.bar, 32 * ord); ord++; }
  }
}

extern "C" void kernel_launch(void* const* d_in, const int* in_sizes, int n_in,
                              void* d_out, int out_size, void* d_ws, size_t ws_size,
                              hipStream_t stream) {
  const float* emb   = (const float*)d_in[0];
  const float* Wih   = (const float*)d_in[1];
  const float* Whh   = (const float*)d_in[2];
  const float* bih   = (const float*)d_in[3];
  const float* bhh   = (const float*)d_in[4];
  const float* ztW   = (const float*)d_in[5];
  const float* ztb   = (const float*)d_in[6];
  const float* rtW   = (const float*)d_in[7];
  const float* rtb   = (const float*)d_in[8];
  const float* htW   = (const float*)d_in[9];
  const float* htb   = (const float*)d_in[10];
  const float* decW  = (const float*)d_in[11];
  const float* decb  = (const float*)d_in[12];
  const float* inith = (const float*)d_in[13];
  const int* word    = (const int*)d_in[14];
  const int* seq     = (const int*)d_in[15];
  float* out = (float*)d_out;

  char* ws = (char*)d_ws;
  size_t off = 0;
  auto alloc = [&](size_t bytes) {
    size_t o = off;
    off += (bytes + 255) & ~(size_t)255;
    return o;
  };
  unsigned short* xbf   = (unsigned short*)(ws + alloc(4096ull * 512 * 2));
  unsigned short* wihbf = (unsigned short*)(ws + alloc(1536ull * 512 * 2));
  unsigned short* decbf = (unsigned short*)(ws + alloc(32000ull * 512 * 2));
  float* wemb           = (float*)(ws + alloc(64ull * 512 * 4));
  float* ztp            = (float*)(ws + alloc(64ull * 512 * 4));
  float* rtp            = (float*)(ws + alloc(64ull * 512 * 4));
  float* gi             = (float*)(ws + alloc(4096ull * 1536 * 4));
  unsigned short* outsb = (unsigned short*)(ws + alloc(4096ull * 512 * 2));
  _Float16* hcur        = (_Float16*)(ws + alloc(64ull * 512 * 2));
  _Float16* hgru        = (_Float16*)(ws + alloc(64ull * 512 * 2));
  _Float16* rw          = (_Float16*)(ws + alloc(64ull * 512 * 2));
  unsigned* bar         = (unsigned*)(ws + alloc(256));

  hipLaunchKernelGGL(k_gather, dim3(4160), dim3(128), 0, stream,
                     emb, seq, word, xbf, wemb);
  hipLaunchKernelGGL(k_conv, dim3(33536), dim3(128), 0, stream,
                     Wih, decW, wihbf, decbf);
  hipLaunchKernelGGL(k_pre, dim3(256), dim3(256), 0, stream,
                     ztW, ztb, rtW, rtb, wemb, ztp, rtp);
  hipLaunchKernelGGL(k_gemm_bt, dim3(384), dim3(256), 0, stream,
                     xbf, wihbf, gi, bih, 4096, 1536, 512);
  hipMemsetAsync(bar, 0, 256, stream);
  RnnP p{Whh, ztW, rtW, htW, gi, ztp, rtp, wemb, inith, bhh, htb,
         hcur, hgru, rw, outsb, out + 4096ull * 32000, bar};
  hipLaunchKernelGGL(k_rnn2, dim3(32), dim3(256), 0, stream, p);
  hipLaunchKernelGGL(k_gemm_bt, dim3(8000), dim3(256), 0, stream,
                     outsb, decbf, out, decb, 4096, 32000, 512);
}

// Round 4
// 1325.862 us; speedup vs baseline: 1.6695x; 1.1432x over previous
//
#include <hip/hip_runtime.h>
#include <stdint.h>

#define GAS __attribute__((address_space(1)))
#define LAS __attribute__((address_space(3)))

typedef __bf16 bf16x8 __attribute__((ext_vector_type(8)));
typedef _Float16 f16x8 __attribute__((ext_vector_type(8)));
typedef float f32x4 __attribute__((ext_vector_type(4)));

__device__ __forceinline__ unsigned short f2bf(float f) {
  unsigned u = __float_as_uint(f);
  unsigned r = (u + 0x7FFFu + ((u >> 16) & 1u)) >> 16;
  return (unsigned short)r;
}

__device__ __forceinline__ float sigmoidf(float x) {
  return 1.f / (1.f + expf(-x));
}

// ---- device-coherent (MALL) exchange primitives ------------------------------
__device__ __forceinline__ void st2c(_Float16* p, _Float16 v) {
  unsigned short u = __builtin_bit_cast(unsigned short, v);
  __hip_atomic_store((unsigned short*)p, u, __ATOMIC_RELAXED, __HIP_MEMORY_SCOPE_AGENT);
}

// plain (non-atomic) 16B load that bypasses L1+L2 -> coherent at MALL.
// NOTE: result is in-flight until an explicit s_waitcnt vmcnt(0)!
__device__ __forceinline__ f16x8 ld16c(const _Float16* p) {
  f32x4 r;
  asm volatile("global_load_dwordx4 %0, %1, off sc0 sc1"
               : "=v"(r) : "v"(p) : "memory");
  return __builtin_bit_cast(f16x8, r);
}

// ---------------- gather: x_bf16 [4096,512] from seq; word_emb f32 [64,512] ----
__global__ __launch_bounds__(128) void k_gather(
    const float* __restrict__ emb, const int* __restrict__ seq,
    const int* __restrict__ word, unsigned short* __restrict__ xbf,
    float* __restrict__ wemb) {
  int row = blockIdx.x;
  int tid = threadIdx.x;
  if (row < 4096) {
    const float* src = emb + (size_t)seq[row] * 512;
    unsigned short* dst = xbf + (size_t)row * 512;
    for (int e = tid; e < 512; e += 128) dst[e] = f2bf(src[e]);
  } else {
    int b = row - 4096;
    const float* src = emb + (size_t)word[b] * 512;
    float* dst = wemb + (size_t)b * 512;
    for (int e = tid; e < 512; e += 128) dst[e] = src[e];
  }
}

// ---------------- weight conversion: wih_bf [1536,512], dec_bf [32000,512] ----
__global__ __launch_bounds__(128) void k_conv(
    const float* __restrict__ Wih, const float* __restrict__ decW,
    unsigned short* __restrict__ wih_bf, unsigned short* __restrict__ dec_bf) {
  int row = blockIdx.x;
  int tid = threadIdx.x;
  if (row < 1536) {
    const float* s = Wih + (size_t)row * 512;
    unsigned short* d = wih_bf + (size_t)row * 512;
    for (int e = tid; e < 512; e += 128) d[e] = f2bf(s[e]);
  } else {
    int o = row - 1536;
    const float* s = decW + (size_t)o * 512;
    unsigned short* d = dec_bf + (size_t)o * 512;
    for (int e = tid; e < 512; e += 128) d[e] = f2bf(s[e]);
  }
}

// ---------------- step-invariant gate preactivations from word_emb ------------
__global__ __launch_bounds__(256) void k_pre(
    const float* __restrict__ ztW, const float* __restrict__ ztb,
    const float* __restrict__ rtW, const float* __restrict__ rtb,
    const float* __restrict__ wemb, float* __restrict__ ztp,
    float* __restrict__ rtp) {
  int idx = blockIdx.x * 256 + threadIdx.x;
  int b = idx >> 10, o = idx & 1023;
  const float4* we = (const float4*)(wemb + (size_t)b * 512);
  const float4* wr;
  float acc;
  if (o < 512) { wr = (const float4*)(ztW + (size_t)o * 1024); acc = ztb[o]; }
  else { wr = (const float4*)(rtW + (size_t)(o - 512) * 1024); acc = rtb[o - 512]; }
  for (int c = 0; c < 128; ++c) {
    float4 w = wr[c], e = we[c];
    acc += w.x * e.x + w.y * e.y + w.z * e.z + w.w * e.w;
  }
  if (o < 512) ztp[(size_t)b * 512 + o] = acc;
  else rtp[(size_t)b * 512 + (o - 512)] = acc;
}

// ---------------- bf16 GEMM, C[m,n] = sum_k A[m,k]*B[n,k] + bias[n] ----------
__global__ __launch_bounds__(256) void k_gemm_bt(
    const unsigned short* __restrict__ A, const unsigned short* __restrict__ B,
    float* __restrict__ C, const float* __restrict__ bias,
    int M, int N, int K) {
  __shared__ __align__(16) unsigned short As[128 * 32];
  __shared__ __align__(16) unsigned short Bs[128 * 32];
  int nt = N >> 7;
  int nwg = gridDim.x;
  int bid = blockIdx.x;
  int swz = (bid & 7) * (nwg >> 3) + (bid >> 3);  // XCD swizzle (nwg % 8 == 0)
  int m0 = (swz / nt) << 7, n0 = (swz % nt) << 7;
  int tid = threadIdx.x;
  int l = tid & 63, w = tid >> 6;
  int wr = w >> 1, wc = w & 1;
  int lr = l & 15, lk = l >> 4;
  f32x4 acc[4][4] = {};
  for (int k0 = 0; k0 < K; k0 += 32) {
#pragma unroll
    for (int i = 0; i < 2; ++i) {
      int c = w * 2 + i;
      int off = c * 1024 + l * 16;
      int row = off >> 6, kb = off & 63;
      const char* ga = (const char*)A + ((size_t)(m0 + row) * K + k0) * 2 + kb;
      const char* gb = (const char*)B + ((size_t)(n0 + row) * K + k0) * 2 + kb;
      __builtin_amdgcn_global_load_lds((const GAS void*)ga,
                                       (LAS void*)((char*)As + c * 1024), 16, 0, 0);
      __builtin_amdgcn_global_load_lds((const GAS void*)gb,
                                       (LAS void*)((char*)Bs + c * 1024), 16, 0, 0);
    }
    asm volatile("s_waitcnt vmcnt(0)" ::: "memory");
    __syncthreads();
    bf16x8 af[4], bfr[4];
#pragma unroll
    for (int i = 0; i < 4; ++i)
      af[i] = *(const bf16x8*)&As[(wr * 64 + i * 16 + lr) * 32 + lk * 8];
#pragma unroll
    for (int i = 0; i < 4; ++i)
      bfr[i] = *(const bf16x8*)&Bs[(wc * 64 + i * 16 + lr) * 32 + lk * 8];
#pragma unroll
    for (int i = 0; i < 4; ++i)
#pragma unroll
      for (int jj = 0; jj < 4; ++jj)
        acc[i][jj] = __builtin_amdgcn_mfma_f32_16x16x32_bf16(af[i], bfr[jj], acc[i][jj], 0, 0, 0);
    __syncthreads();
  }
#pragma unroll
  for (int jj = 0; jj < 4; ++jj) {
    int col = n0 + wc * 64 + jj * 16 + lr;
    float bv = bias ? bias[col] : 0.f;
#pragma unroll
    for (int i = 0; i < 4; ++i) {
      int rb = m0 + wr * 64 + i * 16 + lk * 4;
#pragma unroll
      for (int q = 0; q < 4; ++q)
        C[(size_t)(rb + q) * N + col] = acc[i][jj][q] + bv;
    }
  }
}

// ---------------- recurrence: 32 wgs, output-column ownership, LDS weights ----
// Exchange via MALL-coherent loads/stores. Barrier = per-wg flag slot (64B
// apart) + every wave polls all 32 flags in ONE vector load (no RMW, no sleep).
struct RnnP {
  const float *Whh, *ztW, *rtW, *htW;
  const float *gi, *ztp, *rtp, *wemb, *inith, *bhh, *htb;
  _Float16 *hcur, *hgru, *rw;
  unsigned short *outsb;
  float *hfin;
  unsigned *flags;
};

__device__ __forceinline__ void gbarf(unsigned* flags, int g, unsigned phase) {
  asm volatile("s_waitcnt vmcnt(0)" ::: "memory");  // my stores are at MALL
  __syncthreads();                                  // whole wg drained & arrived
  if (threadIdx.x == 0)
    __hip_atomic_store(flags + (size_t)g * 16, phase, __ATOMIC_RELAXED,
                       __HIP_MEMORY_SCOPE_AGENT);
  int lane = threadIdx.x & 63;
  unsigned v;
  do {
    v = (lane < 32)
            ? __hip_atomic_load(flags + (size_t)lane * 16, __ATOMIC_RELAXED,
                                __HIP_MEMORY_SCOPE_AGENT)
            : phase;
  } while (!__all(v >= phase));
  // no trailing syncthreads: each wave self-releases when all flags visible
}

// acc[n] += A[64,512] (rows 16w..16w+16) x WL-slice; A read via 16B MALL loads,
// all issued upfront, single vmcnt drain, sched_barrier to pin MFMAs after it.
template <int NT>
__device__ __forceinline__ void mm_phase(f32x4* acc, const _Float16* A,
                                         const _Float16* WLrow, int w, int lr, int lk) {
  f16x8 af[16];
  const _Float16* arow = A + ((size_t)(16 * w + lr)) * 512 + lk * 8;
#pragma unroll
  for (int c = 0; c < 16; ++c) af[c] = ld16c(arow + c * 32);
  asm volatile("s_waitcnt vmcnt(0)" ::: "memory");
  __builtin_amdgcn_sched_barrier(0);
#pragma unroll
  for (int c = 0; c < 16; ++c) {
#pragma unroll
    for (int n = 0; n < NT; ++n) {
      f16x8 bb = *(const f16x8*)(WLrow + (n * 16 + lr) * 520 + c * 32 + lk * 8);
      acc[n] = __builtin_amdgcn_mfma_f32_16x16x32_f16(af[c], bb, acc[n], 0, 0, 0);
    }
  }
}

__global__ __launch_bounds__(256) void k_rnn2(RnnP p) {
  const int g = blockIdx.x, tid = threadIdx.x;
  const int w = tid >> 6, l = tid & 63;
  const int lr = l & 15, lk = l >> 4;
  // 112 rows x 520 halfs (512 + 8 pad -> row stride 1040B, 16B aligned)
  __shared__ _Float16 WL[112 * 520];
  // ---- one-time: weights f32 -> f16 into LDS ----
  for (int idx = tid; idx < 112 * 512; idx += 256) {
    int rr = idx >> 9, e = idx & 511;
    const float* src;
    if (rr < 48) {
      int gate = rr >> 4, i = rr & 15;
      src = p.Whh + ((size_t)(gate * 512 + g * 16 + i)) * 512 + e;
    } else if (rr < 96) {
      int r2 = rr - 48, gate = r2 >> 4, i = r2 & 15;
      const float* base = gate == 0 ? p.ztW : (gate == 1 ? p.rtW : p.htW);
      src = base + ((size_t)(g * 16 + i)) * 1024 + 512 + e;
    } else {
      int i = rr - 96;
      src = p.htW + ((size_t)(g * 16 + i)) * 1024 + e;
    }
    WL[rr * 520 + e] = (_Float16)(*src);
  }
  // ---- per-lane owned coordinates: col j, batch rows brow..brow+3 ----
  const int j = g * 16 + lr;
  const int brow = 16 * w + lk * 4;
  f32x4 hprev, zp, rp, wev;
#pragma unroll
  for (int q = 0; q < 4; ++q) {
    int b = brow + q;
    hprev[q] = p.inith[(size_t)b * 512 + j];
    zp[q] = p.ztp[(size_t)b * 512 + j];
    rp[q] = p.rtp[(size_t)b * 512 + j];
    wev[q] = p.wemb[(size_t)b * 512 + j];
    st2c(&p.hcur[(size_t)b * 512 + j], (_Float16)hprev[q]);
  }
  const float br = p.bhh[j], bz = p.bhh[512 + j], bn = p.bhh[1024 + j];
  const float bht = p.htb[j];
  // gi prefetch registers (plain cached loads; gi is immutable intermediate)
  float gir[12];
#pragma unroll
  for (int q = 0; q < 4; ++q) {
    const float* git = p.gi + (size_t)(brow + q) * 1536;
    gir[q * 3 + 0] = git[j];
    gir[q * 3 + 1] = git[512 + j];
    gir[q * 3 + 2] = git[1024 + j];
  }
  unsigned ph = 1;
  gbarf(p.flags, g, ph); ph++;
  for (int t = 0; t < 64; ++t) {
    // ---- phase 1: gates r,z,n ; h_gru ----
    f32x4 acc1[3] = {};
    mm_phase<3>(acc1, p.hcur, &WL[0], w, lr, lk);
    f32x4 hg;
#pragma unroll
    for (int q = 0; q < 4; ++q) {
      int b = brow + q;
      float r = sigmoidf(gir[q * 3 + 0] + br + acc1[0][q]);
      float z = sigmoidf(gir[q * 3 + 1] + bz + acc1[1][q]);
      float n = tanhf(gir[q * 3 + 2] + r * (acc1[2][q] + bn));
      float hgq = (1.f - z) * n + z * hprev[q];
      hg[q] = hgq;
      st2c(&p.hgru[(size_t)b * 512 + j], (_Float16)hgq);
      p.outsb[((size_t)t * 64 + b) * 512 + j] = f2bf(hgq);
    }
    gbarf(p.flags, g, ph); ph++;
    // ---- phase 2: zt, rt, htB ----
    f32x4 acc2[3] = {};
    mm_phase<3>(acc2, p.hgru, &WL[48 * 520], w, lr, lk);
    f32x4 zt, htB;
#pragma unroll
    for (int q = 0; q < 4; ++q) {
      int b = brow + q;
      float ztq = sigmoidf(zp[q] + acc2[0][q]);
      float rtq = sigmoidf(rp[q] + acc2[1][q]);
      zt[q] = ztq;
      htB[q] = acc2[2][q];
      st2c(&p.rw[(size_t)b * 512 + j], (_Float16)(rtq * wev[q]));
    }
    gbarf(p.flags, g, ph); ph++;
    // ---- phase 3: htA ; h_new (prefetch next step's gi first, hides latency) ----
    if (t < 63) {
      const float* git = p.gi + (size_t)(t + 1) * 64 * 1536;
#pragma unroll
      for (int q = 0; q < 4; ++q) {
        const float* gb = git + (size_t)(brow + q) * 1536;
        gir[q * 3 + 0] = gb[j];
        gir[q * 3 + 1] = gb[512 + j];
        gir[q * 3 + 2] = gb[1024 + j];
      }
    }
    f32x4 acc3[1] = {};
    mm_phase<1>(acc3, p.rw, &WL[96 * 520], w, lr, lk);
#pragma unroll
    for (int q = 0; q < 4; ++q) {
      int b = brow + q;
      float htl = tanhf(acc3[0][q] + htB[q] + bht);
      float hn2 = (1.f - zt[q]) * hg[q] + zt[q] * htl;
      hprev[q] = hn2;
      if (t < 63) st2c(&p.hcur[(size_t)b * 512 + j], (_Float16)hn2);
      else p.hfin[(size_t)b * 512 + j] = hn2;
    }
    if (t < 63) { gbarf(p.flags, g, ph); ph++; }
  }
}

extern "C" void kernel_launch(void* const* d_in, const int* in_sizes, int n_in,
                              void* d_out, int out_size, void* d_ws, size_t ws_size,
                              hipStream_t stream) {
  const float* emb   = (const float*)d_in[0];
  const float* Wih   = (const float*)d_in[1];
  const float* Whh   = (const float*)d_in[2];
  const float* bih   = (const float*)d_in[3];
  const float* bhh   = (const float*)d_in[4];
  const float* ztW   = (const float*)d_in[5];
  const float* ztb   = (const float*)d_in[6];
  const float* rtW   = (const float*)d_in[7];
  const float* rtb   = (const float*)d_in[8];
  const float* htW   = (const float*)d_in[9];
  const float* htb   = (const float*)d_in[10];
  const float* decW  = (const float*)d_in[11];
  const float* decb  = (const float*)d_in[12];
  const float* inith = (const float*)d_in[13];
  const int* word    = (const int*)d_in[14];
  const int* seq     = (const int*)d_in[15];
  float* out = (float*)d_out;

  char* ws = (char*)d_ws;
  size_t off = 0;
  auto alloc = [&](size_t bytes) {
    size_t o = off;
    off += (bytes + 255) & ~(size_t)255;
    return o;
  };
  unsigned short* xbf   = (unsigned short*)(ws + alloc(4096ull * 512 * 2));
  unsigned short* wihbf = (unsigned short*)(ws + alloc(1536ull * 512 * 2));
  unsigned short* decbf = (unsigned short*)(ws + alloc(32000ull * 512 * 2));
  float* wemb           = (float*)(ws + alloc(64ull * 512 * 4));
  float* ztp            = (float*)(ws + alloc(64ull * 512 * 4));
  float* rtp            = (float*)(ws + alloc(64ull * 512 * 4));
  float* gi             = (float*)(ws + alloc(4096ull * 1536 * 4));
  unsigned short* outsb = (unsigned short*)(ws + alloc(4096ull * 512 * 2));
  _Float16* hcur        = (_Float16*)(ws + alloc(64ull * 512 * 2));
  _Float16* hgru        = (_Float16*)(ws + alloc(64ull * 512 * 2));
  _Float16* rw          = (_Float16*)(ws + alloc(64ull * 512 * 2));
  unsigned* flags       = (unsigned*)(ws + alloc(32 * 64));

  hipLaunchKernelGGL(k_gather, dim3(4160), dim3(128), 0, stream,
                     emb, seq, word, xbf, wemb);
  hipLaunchKernelGGL(k_conv, dim3(33536), dim3(128), 0, stream,
                     Wih, decW, wihbf, decbf);
  hipLaunchKernelGGL(k_pre, dim3(256), dim3(256), 0, stream,
                     ztW, ztb, rtW, rtb, wemb, ztp, rtp);
  hipLaunchKernelGGL(k_gemm_bt, dim3(384), dim3(256), 0, stream,
                     xbf, wihbf, gi, bih, 4096, 1536, 512);
  hipMemsetAsync(flags, 0, 32 * 64, stream);
  RnnP p{Whh, ztW, rtW, htW, gi, ztp, rtp, wemb, inith, bhh, htb,
         hcur, hgru, rw, outsb, out + 4096ull * 32000, flags};
  hipLaunchKernelGGL(k_rnn2, dim3(32), dim3(256), 0, stream, p);
  hipLaunchKernelGGL(k_gemm_bt, dim3(8000), dim3(256), 0, stream,
                     outsb, decbf, out, decb, 4096, 32000, 512);
}